// Round 1
// baseline (158.589 us; speedup 1.0000x reference)
//
#include <hip/hip_runtime.h>

#define BATCH 8
#define NPTS 9225
#define MQ 4096
#define CAP 64
#define QPW 4   // queries per wave

__global__ __launch_bounds__(256) void nbr_kernel(
    const float* __restrict__ data, const float* __restrict__ queries,
    const float* __restrict__ radius_p, int* __restrict__ nbr_idx,
    int* __restrict__ counts) {
#pragma clang fp contract(off)
  const int wave = (blockIdx.x * blockDim.x + threadIdx.x) >> 6;
  const int lane = threadIdx.x & 63;
  const int qbase = wave * QPW;
  if (qbase >= BATCH * MQ) return;
  const int b = qbase / MQ;
  const float r = radius_p[0];
  const float r2 = r * r;

  float qx[QPW], qy[QPW], qn[QPW];
  int cnt[QPW];
#pragma unroll
  for (int j = 0; j < QPW; ++j) {
    const int q = qbase + j;
    qx[j] = queries[q * 2 + 0];
    qy[j] = queries[q * 2 + 1];
    qn[j] = qx[j] * qx[j] + qy[j] * qy[j];   // mul,mul,add — no fma (matches np)
    cnt[j] = 0;
  }
  const float* dptr = data + (size_t)b * NPTS * 2;
  const unsigned long long below = (1ull << lane) - 1ull;

  for (int c = 0; c < NPTS; c += 64) {
    const int i = c + lane;
    float dx = 0.f, dy = 0.f, dn = 0.f;
    const bool valid = (i < NPTS);
    if (valid) {
      dx = dptr[i * 2 + 0];
      dy = dptr[i * 2 + 1];
      dn = dx * dx + dy * dy;                // mul,mul,add — no fma
    }
#pragma unroll
    for (int j = 0; j < QPW; ++j) {
      const float cross = qx[j] * dx + qy[j] * dy;   // mul,mul,add — no fma
      const float s = (qn[j] + dn) - 2.0f * cross;   // matches np op order
      const bool in = valid && (s <= r2);
      const unsigned long long mask = __ballot(in);
      if (in) {
        const int pos = cnt[j] + __popcll(mask & below);
        if (pos < CAP) nbr_idx[(size_t)(qbase + j) * CAP + pos] = i;
      }
      cnt[j] += __popcll(mask);
    }
  }
#pragma unroll
  for (int j = 0; j < QPW; ++j) {
    for (int p = cnt[j] + lane; p < CAP; p += 64)
      nbr_idx[(size_t)(qbase + j) * CAP + p] = -1;
    if (lane == 0) counts[qbase + j] = cnt[j];
  }
}

// Per-batch exclusive scan of 4096 counts -> row_splits[b][0..4096]
__global__ __launch_bounds__(256) void scan_kernel(const int* __restrict__ counts,
                                                   int* __restrict__ row_splits) {
  const int b = blockIdx.x;
  const int t = threadIdx.x;
  const int T = 256;
  const int PER = MQ / T;  // 16
  __shared__ int partial[T];
  const int* c = counts + b * MQ;
  int local[PER];
  int sum = 0;
#pragma unroll
  for (int k = 0; k < PER; ++k) { local[k] = c[t * PER + k]; sum += local[k]; }
  partial[t] = sum;
  __syncthreads();
  // Hillis-Steele inclusive scan over 256 partials
  for (int off = 1; off < T; off <<= 1) {
    int v = (t >= off) ? partial[t - off] : 0;
    __syncthreads();
    partial[t] += v;
    __syncthreads();
  }
  const int excl = (t == 0) ? 0 : partial[t - 1];
  int* rs = row_splits + b * (MQ + 1);
  if (t == 0) rs[0] = 0;
  int run = excl;
#pragma unroll
  for (int k = 0; k < PER; ++k) { run += local[k]; rs[t * PER + k + 1] = run; }
}

extern "C" void kernel_launch(void* const* d_in, const int* in_sizes, int n_in,
                              void* d_out, int out_size, void* d_ws, size_t ws_size,
                              hipStream_t stream) {
  const float* data    = (const float*)d_in[0];
  const float* queries = (const float*)d_in[1];
  const float* radius  = (const float*)d_in[2];
  int* out        = (int*)d_out;
  int* nbr_idx    = out;                       // BATCH*MQ*CAP
  int* row_splits = out + BATCH * MQ * CAP;    // BATCH*(MQ+1)
  int* counts     = (int*)d_ws;                // BATCH*MQ ints = 128 KiB

  const int waves  = BATCH * MQ / QPW;         // 8192
  const int blocks = waves * 64 / 256;         // 2048
  hipLaunchKernelGGL(nbr_kernel, dim3(blocks), dim3(256), 0, stream,
                     data, queries, radius, nbr_idx, counts);
  hipLaunchKernelGGL(scan_kernel, dim3(BATCH), dim3(256), 0, stream,
                     counts, row_splits);
}

// Round 2
// 145.126 us; speedup vs baseline: 1.0928x; 1.0928x over previous
//
#include <hip/hip_runtime.h>

#define BATCH 8
#define NPTS 9225
#define MQ 4096
#define CAP 64
#define QPW 8           // queries per wave
#define FULL (NPTS & ~63)   // 9216 = 144 full chunks
#define TAIL (NPTS - FULL)  // 9

__global__ __launch_bounds__(256) void nbr_kernel(
    const float* __restrict__ data, const float* __restrict__ queries,
    const float* __restrict__ radius_p, int* __restrict__ nbr_idx,
    int* __restrict__ counts) {
#pragma clang fp contract(off)
  const int wave = (blockIdx.x * blockDim.x + threadIdx.x) >> 6;
  const int lane = threadIdx.x & 63;
  const int qbase = wave * QPW;
  if (qbase >= BATCH * MQ) return;
  const int b = qbase / MQ;
  const float r = radius_p[0];
  const float r2 = r * r;

  float qx[QPW], qy[QPW], qn[QPW];
  int cnt[QPW];
  int* outp[QPW];
  const float2* qptr = (const float2*)queries;
#pragma unroll
  for (int j = 0; j < QPW; ++j) {
    const float2 qv = qptr[qbase + j];
    qx[j] = qv.x;
    qy[j] = qv.y;
    qn[j] = qx[j] * qx[j] + qy[j] * qy[j];   // mul,mul,add — no fma (matches np)
    cnt[j] = 0;
    outp[j] = nbr_idx + (size_t)(qbase + j) * CAP;  // uniform -> saddr stores
  }
  const float2* dptr = (const float2*)(data + (size_t)b * NPTS * 2);
  const unsigned long long below = (1ull << lane) - 1ull;

  // 144 full chunks, no tail predicate
  for (int c = 0; c < FULL; c += 64) {
    const float2 dv = dptr[c + lane];
    const float dx = dv.x, dy = dv.y;
    const float dn = dx * dx + dy * dy;              // mul,mul,add — no fma
#pragma unroll
    for (int j = 0; j < QPW; ++j) {
      const float t = qn[j] + dn;
      const float cross = qx[j] * dx + qy[j] * dy;   // mul,mul,add — no fma
      const float s = t - 2.0f * cross;              // matches np op order
      const bool in = (s <= r2);
      const unsigned long long mask = __ballot(in);
      if (mask != 0ull) {                            // wave-uniform skip (~84%)
        if (in) {
          const int pos = cnt[j] + __popcll(mask & below);
          if (pos < CAP) outp[j][pos] = c + lane;
        }
        cnt[j] += __popcll(mask);
      }
    }
  }
  // 9-point tail
  {
    const int c = FULL;
    const bool valid = (lane < TAIL);
    float dx = 0.f, dy = 0.f, dn = 0.f;
    if (valid) {
      const float2 dv = dptr[c + lane];
      dx = dv.x; dy = dv.y;
      dn = dx * dx + dy * dy;
    }
#pragma unroll
    for (int j = 0; j < QPW; ++j) {
      const float t = qn[j] + dn;
      const float cross = qx[j] * dx + qy[j] * dy;
      const float s = t - 2.0f * cross;
      const bool in = valid && (s <= r2);
      const unsigned long long mask = __ballot(in);
      if (in) {
        const int pos = cnt[j] + __popcll(mask & below);
        if (pos < CAP) outp[j][pos] = c + lane;
      }
      cnt[j] += __popcll(mask);
    }
  }
#pragma unroll
  for (int j = 0; j < QPW; ++j) {
    for (int p = cnt[j] + lane; p < CAP; p += 64)
      outp[j][p] = -1;
    if (lane == 0) counts[qbase + j] = cnt[j];
  }
}

// Per-batch exclusive scan of 4096 counts -> row_splits[b][0..4096]
__global__ __launch_bounds__(256) void scan_kernel(const int* __restrict__ counts,
                                                   int* __restrict__ row_splits) {
  const int b = blockIdx.x;
  const int t = threadIdx.x;
  const int T = 256;
  const int PER = MQ / T;  // 16
  __shared__ int partial[T];
  const int* c = counts + b * MQ;
  int local[PER];
  int sum = 0;
#pragma unroll
  for (int k = 0; k < PER; ++k) { local[k] = c[t * PER + k]; sum += local[k]; }
  partial[t] = sum;
  __syncthreads();
  for (int off = 1; off < T; off <<= 1) {
    int v = (t >= off) ? partial[t - off] : 0;
    __syncthreads();
    partial[t] += v;
    __syncthreads();
  }
  const int excl = (t == 0) ? 0 : partial[t - 1];
  int* rs = row_splits + b * (MQ + 1);
  if (t == 0) rs[0] = 0;
  int run = excl;
#pragma unroll
  for (int k = 0; k < PER; ++k) { run += local[k]; rs[t * PER + k + 1] = run; }
}

extern "C" void kernel_launch(void* const* d_in, const int* in_sizes, int n_in,
                              void* d_out, int out_size, void* d_ws, size_t ws_size,
                              hipStream_t stream) {
  const float* data    = (const float*)d_in[0];
  const float* queries = (const float*)d_in[1];
  const float* radius  = (const float*)d_in[2];
  int* out        = (int*)d_out;
  int* nbr_idx    = out;                       // BATCH*MQ*CAP
  int* row_splits = out + BATCH * MQ * CAP;    // BATCH*(MQ+1)
  int* counts     = (int*)d_ws;                // BATCH*MQ ints = 128 KiB

  const int waves  = BATCH * MQ / QPW;         // 4096
  const int blocks = waves * 64 / 256;         // 1024
  hipLaunchKernelGGL(nbr_kernel, dim3(blocks), dim3(256), 0, stream,
                     data, queries, radius, nbr_idx, counts);
  hipLaunchKernelGGL(scan_kernel, dim3(BATCH), dim3(256), 0, stream,
                     counts, row_splits);
}

// Round 3
// 92.980 us; speedup vs baseline: 1.7056x; 1.5608x over previous
//
#include <hip/hip_runtime.h>

#define BATCH 8
#define NPTS 9225
#define MQ 4096
#define CAP 64
#define GRID 32
#define NCELLS (GRID * GRID)   // 1024, cell = 1/32 = 0.03125 > r = 0.03

__device__ __forceinline__ int cell_of(float x, float y) {
  int cx = (int)(x * (float)GRID);
  int cy = (int)(y * (float)GRID);
  cx = min(max(cx, 0), GRID - 1);
  cy = min(max(cy, 0), GRID - 1);
  return cy * GRID + cx;
}

__global__ __launch_bounds__(256) void zero_kernel(int* __restrict__ p, int n) {
  int i = blockIdx.x * blockDim.x + threadIdx.x;
  if (i < n) p[i] = 0;
}

__global__ __launch_bounds__(256) void hist_kernel(const float* __restrict__ data,
                                                   int* __restrict__ cell_counts) {
  int idx = blockIdx.x * blockDim.x + threadIdx.x;
  if (idx >= BATCH * NPTS) return;
  int b = idx / NPTS;
  const float2 p = ((const float2*)data)[idx];
  atomicAdd(&cell_counts[b * NCELLS + cell_of(p.x, p.y)], 1);
}

// one block per batch: exclusive scan of 1024 cell counts
__global__ __launch_bounds__(1024) void cellscan_kernel(const int* __restrict__ cell_counts,
                                                        int* __restrict__ cell_starts,
                                                        int* __restrict__ cursors) {
  __shared__ int sc[NCELLS];
  const int b = blockIdx.x;
  const int t = threadIdx.x;
  const int v = cell_counts[b * NCELLS + t];
  sc[t] = v;
  __syncthreads();
  for (int off = 1; off < NCELLS; off <<= 1) {
    int u = (t >= off) ? sc[t - off] : 0;
    __syncthreads();
    sc[t] += u;
    __syncthreads();
  }
  const int incl = sc[t];
  const int excl = incl - v;
  cell_starts[b * (NCELLS + 1) + t] = excl;
  cursors[b * NCELLS + t] = excl;
  if (t == NCELLS - 1) cell_starts[b * (NCELLS + 1) + NCELLS] = incl;
}

__global__ __launch_bounds__(256) void scatter_kernel(const float* __restrict__ data,
                                                      int* __restrict__ cursors,
                                                      float2* __restrict__ sdata,
                                                      int* __restrict__ sidx) {
  int idx = blockIdx.x * blockDim.x + threadIdx.x;
  if (idx >= BATCH * NPTS) return;
  int b = idx / NPTS;
  int i = idx - b * NPTS;  // batch-local original index
  const float2 p = ((const float2*)data)[idx];
  int pos = atomicAdd(&cursors[b * NCELLS + cell_of(p.x, p.y)], 1);
  sdata[b * NPTS + pos] = p;
  sidx[b * NPTS + pos] = i;
}

// one wave per query
__global__ __launch_bounds__(256) void search_kernel(
    const float* __restrict__ queries, const float* __restrict__ radius_p,
    const int* __restrict__ cell_starts, const float2* __restrict__ sdata,
    const int* __restrict__ sidx, int* __restrict__ nbr_idx,
    int* __restrict__ counts) {
#pragma clang fp contract(off)
  __shared__ int hitbuf[4][CAP];
  const int wave_g = (blockIdx.x * blockDim.x + threadIdx.x) >> 6;
  const int lane = threadIdx.x & 63;
  const int w = (threadIdx.x >> 6) & 3;
  if (wave_g >= BATCH * MQ) return;
  const int q = wave_g;
  const int b = q >> 12;  // MQ = 4096
  const float r = radius_p[0];
  const float r2 = r * r;
  const float2 qv = ((const float2*)queries)[q];
  const float qx = qv.x, qy = qv.y;
  const float qn = qx * qx + qy * qy;  // mul,mul,add — no fma (matches np)

  int cx = min(max((int)(qx * (float)GRID), 0), GRID - 1);
  int cy = min(max((int)(qy * (float)GRID), 0), GRID - 1);
  const int x0 = max(cx - 1, 0), x1 = min(cx + 1, GRID - 1);
  const int y0 = max(cy - 1, 0), y1 = min(cy + 1, GRID - 1);

  const unsigned long long below = (1ull << lane) - 1ull;
  const int csbase = b * (NCELLS + 1);
  const float2* sd = sdata + b * NPTS;
  const int* si = sidx + b * NPTS;
  int h = 0;

  for (int y = y0; y <= y1; ++y) {
    const int s0 = cell_starts[csbase + y * GRID + x0];
    const int s1 = cell_starts[csbase + y * GRID + x1 + 1];
    for (int off = s0; off < s1; off += 64) {
      const int i = off + lane;
      const bool act = (i < s1);
      float dx = 0.f, dy = 0.f;
      int id = 0;
      if (act) {
        const float2 p = sd[i];
        dx = p.x; dy = p.y;
        id = si[i];
      }
      const float dn = dx * dx + dy * dy;            // mul,mul,add — no fma
      const float cross = qx * dx + qy * dy;         // mul,mul,add — no fma
      const float s = (qn + dn) - 2.0f * cross;      // matches np op order
      const bool in = act && (s <= r2);
      const unsigned long long mask = __ballot(in);
      if (in) {
        const int pos = h + __popcll(mask & below);
        if (pos < CAP) hitbuf[w][pos] = id;
      }
      h += __popcll(mask);
    }
  }

  // gather (same-wave LDS RAW: DS ops from one wave execute in order)
  int v = (lane < h && lane < CAP) ? hitbuf[w][lane] : 0x7fffffff;

  // 64-lane bitonic sort, ascending
#pragma unroll
  for (int k = 2; k <= 64; k <<= 1) {
#pragma unroll
    for (int j = k >> 1; j >= 1; j >>= 1) {
      const int other = __shfl_xor(v, j, 64);
      const bool up = ((lane & k) == 0);
      const bool lower = ((lane & j) == 0);
      const bool keep_min = (up == lower);
      v = keep_min ? min(v, other) : max(v, other);
    }
  }

  nbr_idx[(size_t)q * CAP + lane] = (v == 0x7fffffff) ? -1 : v;
  if (lane == 0) counts[q] = h;
}

// Per-batch exclusive scan of 4096 counts -> row_splits[b][0..4096]
__global__ __launch_bounds__(256) void scan_kernel(const int* __restrict__ counts,
                                                   int* __restrict__ row_splits) {
  const int b = blockIdx.x;
  const int t = threadIdx.x;
  const int T = 256;
  const int PER = MQ / T;  // 16
  __shared__ int partial[T];
  const int* c = counts + b * MQ;
  int local[PER];
  int sum = 0;
#pragma unroll
  for (int k = 0; k < PER; ++k) { local[k] = c[t * PER + k]; sum += local[k]; }
  partial[t] = sum;
  __syncthreads();
  for (int off = 1; off < T; off <<= 1) {
    int v = (t >= off) ? partial[t - off] : 0;
    __syncthreads();
    partial[t] += v;
    __syncthreads();
  }
  const int excl = (t == 0) ? 0 : partial[t - 1];
  int* rs = row_splits + b * (MQ + 1);
  if (t == 0) rs[0] = 0;
  int run = excl;
#pragma unroll
  for (int k = 0; k < PER; ++k) { run += local[k]; rs[t * PER + k + 1] = run; }
}

extern "C" void kernel_launch(void* const* d_in, const int* in_sizes, int n_in,
                              void* d_out, int out_size, void* d_ws, size_t ws_size,
                              hipStream_t stream) {
  const float* data    = (const float*)d_in[0];
  const float* queries = (const float*)d_in[1];
  const float* radius  = (const float*)d_in[2];
  int* out        = (int*)d_out;
  int* nbr_idx    = out;                       // BATCH*MQ*CAP
  int* row_splits = out + BATCH * MQ * CAP;    // BATCH*(MQ+1)

  // workspace layout (ints), total ~1.07 MB
  int* counts      = (int*)d_ws;                         // 32768
  int* cell_counts = counts + BATCH * MQ;                // 8192
  int* cell_starts = cell_counts + BATCH * NCELLS;       // 8200
  int* cursors     = cell_starts + BATCH * (NCELLS + 1); // 8192
  int* sidx        = cursors + BATCH * NCELLS;           // 73800
  float2* sdata    = (float2*)(sidx + BATCH * NPTS);     // 73800 float2 (8B-aligned)

  const int npts_blocks = (BATCH * NPTS + 255) / 256;    // 289
  hipLaunchKernelGGL(zero_kernel, dim3((BATCH * NCELLS + 255) / 256), dim3(256), 0, stream,
                     cell_counts, BATCH * NCELLS);
  hipLaunchKernelGGL(hist_kernel, dim3(npts_blocks), dim3(256), 0, stream,
                     data, cell_counts);
  hipLaunchKernelGGL(cellscan_kernel, dim3(BATCH), dim3(NCELLS), 0, stream,
                     cell_counts, cell_starts, cursors);
  hipLaunchKernelGGL(scatter_kernel, dim3(npts_blocks), dim3(256), 0, stream,
                     data, cursors, sdata, sidx);
  hipLaunchKernelGGL(search_kernel, dim3(BATCH * MQ / 4), dim3(256), 0, stream,
                     queries, radius, cell_starts, sdata, sidx, nbr_idx, counts);
  hipLaunchKernelGGL(scan_kernel, dim3(BATCH), dim3(256), 0, stream,
                     counts, row_splits);
}